// Round 5
// baseline (351.284 us; speedup 1.0000x reference)
//
#include <hip/hip_runtime.h>
#include <cfloat>

typedef short  bf16x8 __attribute__((ext_vector_type(8)));
typedef float  f32x4  __attribute__((ext_vector_type(4)));
typedef unsigned int  uint;
typedef unsigned short ushort;

// Problem constants
constexpr int DIM  = 512;
constexpr int NEMB = 1024;
constexpr int HW   = 1024;
constexpr int NROW = 32 * HW;   // 32768

constexpr long long QCOUNT = (long long)32 * 512 * 32 * 32; // 16777216
constexpr long long SOFF   = QCOUNT;
constexpr long long IOFF   = SOFF + 1;

// ---------------- ws layout (bytes) ----------------
// zt: 512 mb x 16 kc tiles of (64r x 32k bf16, swizzled) = 4KB  -> 32 MB each
// et: 8 nc x 16 kc tiles of (128r x 32k bf16, swizzled) = 8KB   -> 1 MB each
constexpr size_t WS_ZHI   = 0;
constexpr size_t WS_ZLO   = 33554432;
constexpr size_t WS_EHI   = 67108864;
constexpr size_t WS_ELO   = 68157440;
constexpr size_t WS_ENORM = 69206016;
constexpr size_t WS_CNT   = 69210112;
constexpr size_t WS_LIST  = 69210368;
constexpr size_t WS_NEED  = WS_LIST + (size_t)NROW * 4;

constexpr float DELTA = 0.125f;  // recheck margin (>>100x bf16-split error bound)

// ---------------- helpers ----------------
__device__ __forceinline__ ushort bf16_rne(float x) {
    union { float f; uint u; } a; a.f = x;
    uint t = a.u + 0x7FFFu + ((a.u >> 16) & 1u);
    return (ushort)(t >> 16);
}
__device__ __forceinline__ float bf16_to_f(ushort h) {
    union { float f; uint u; } a; a.u = ((uint)h) << 16;
    return a.f;
}
__device__ __forceinline__ void gld16(const void* g, void* l) {
    __builtin_amdgcn_global_load_lds(
        (const __attribute__((address_space(1))) void*)g,
        (__attribute__((address_space(3))) void*)l, 16, 0, 0);
}
union PK8 { bf16x8 v; ushort u[8]; };

// granule swizzle for 32k-wide tiles (4 x 16B granules per 64B row):
// slot(r,g) = g ^ (r&3) ^ ((r>>2)&3)  -> 2-way-only bank aliasing on
// 16-lane ds_read_b128 groups (2-way is free, m136). Involution in g.
__device__ __forceinline__ int swz_slot(int r, int g) {
    return g ^ (r & 3) ^ ((r >> 2) & 3);
}

// ---------------- P1: embedding norms + counter zero ----------------
__global__ __launch_bounds__(256) void enorm_prep(const float* __restrict__ e,
                                                  float* __restrict__ enorm,
                                                  int* __restrict__ cnt) {
    if (blockIdx.x == 0 && threadIdx.x == 0) *cnt = 0;
    int gid  = blockIdx.x * 256 + threadIdx.x;
    int wave = gid >> 6;
    int lane = gid & 63;
    if (wave >= NEMB) return;
    const float* row = e + (size_t)wave * DIM;
    float4 a = *reinterpret_cast<const float4*>(row + lane * 8);
    float4 b = *reinterpret_cast<const float4*>(row + lane * 8 + 4);
    float s = a.x*a.x + a.y*a.y + a.z*a.z + a.w*a.w
            + b.x*b.x + b.y*b.y + b.z*b.z + b.w*b.w;
    #pragma unroll
    for (int off = 32; off > 0; off >>= 1) s += __shfl_down(s, off, 64);
    if (lane == 0) enorm[wave] = s;
}

// ---------------- P2: e -> et_hi / et_lo swizzled 128x32 tiles -------------
__global__ __launch_bounds__(256) void eprep(const float* __restrict__ e,
                                             char* __restrict__ et_hi,
                                             char* __restrict__ et_lo) {
    int t   = blockIdx.x * 256 + threadIdx.x;  // 0..65535
    int ke  = t >> 6;
    int kbg = t & 63;                          // global 16B-granule 0..63
    const float* src = e + (size_t)ke * DIM + kbg * 8;
    PK8 h, lo;
    #pragma unroll
    for (int j = 0; j < 8; ++j) {
        float v = src[j];
        ushort hh = bf16_rne(v);
        h.u[j]  = hh;
        lo.u[j] = bf16_rne(v - bf16_to_f(hh));
    }
    int nc = ke >> 7, r = ke & 127, kc = kbg >> 2, kg = kbg & 3;
    size_t byte = ((size_t)(nc * 16 + kc)) * 8192 + (size_t)r * 64
                + ((size_t)swz_slot(r, kg) << 4);
    *reinterpret_cast<bf16x8*>(et_hi + byte) = h.v;
    *reinterpret_cast<bf16x8*>(et_lo + byte) = lo.v;
}

// ---------------- P3: z -> zt_hi / zt_lo swizzled 64x32 tiles (transpose) --
__global__ __launch_bounds__(256) void zprep(const float* __restrict__ z,
                                             char* __restrict__ zt_hi,
                                             char* __restrict__ zt_lo) {
    __shared__ float ls[64][65];
    const int bx = blockIdx.x;
    const int mb = bx >> 3, kcc = bx & 7;      // kcc covers 64 channels
    const int n0 = mb * 64;
    const int b  = n0 >> 10;
    const int hw0 = n0 & (HW - 1);
    const int t = threadIdx.x;
    const int c4 = t >> 6, lane = t & 63;
    #pragma unroll
    for (int rnd = 0; rnd < 16; ++rnd) {
        int cl = c4 + rnd * 4;
        ls[cl][lane] = z[((size_t)(b * DIM + kcc * 64 + cl)) * HW + hw0 + lane];
    }
    __syncthreads();
    for (int g = t; g < 512; g += 256) {
        int r = g >> 3, kbl = g & 7;           // kbl: granule within 64 channels
        PK8 h, lo;
        #pragma unroll
        for (int j = 0; j < 8; ++j) {
            float v = ls[kbl * 8 + j][r];
            ushort hh = bf16_rne(v);
            h.u[j]  = hh;
            lo.u[j] = bf16_rne(v - bf16_to_f(hh));
        }
        int kc_l = kbl >> 2, kg = kbl & 3;
        size_t tile = (size_t)mb * 16 + kcc * 2 + kc_l;
        size_t byte = tile * 4096 + (size_t)r * 64 + ((size_t)swz_slot(r, kg) << 4);
        *reinterpret_cast<bf16x8*>(zt_hi + byte) = h.v;
        *reinterpret_cast<bf16x8*>(zt_lo + byte) = lo.v;
    }
}

// ---------------- Main: 2-phase dbuf bf16-split MFMA + argmin + gather -----
__global__ __launch_bounds__(256) void vq_mfma(const char* __restrict__ zt_hi,
                                               const char* __restrict__ zt_lo,
                                               const char* __restrict__ et_hi,
                                               const char* __restrict__ et_lo,
                                               const float* __restrict__ enorm,
                                               const float* __restrict__ e,
                                               float* __restrict__ out,
                                               int* __restrict__ cnt,
                                               int* __restrict__ list) {
    __shared__ __align__(16) char sA[2][8192];    // [buf]: hi 4KB | lo 4KB
    __shared__ __align__(16) char sB[2][16384];   // [buf]: hi 8KB | lo 8KB
    __shared__ float red_b1[64][2];
    __shared__ float red_b2[64][2];
    __shared__ int   red_i1[64][2];
    __shared__ int   idx_f[64];

    const int t = threadIdx.x;
    const int w = t >> 6, l = t & 63;
    const int lr = l & 15, hg = l >> 4;           // hg = k-granule 0..3
    const int wr = (w >> 1) * 32;                 // wave row offset (0 or 32)
    const int wc = (w & 1) * 64;                  // wave col offset (0 or 64)
    const int mb = blockIdx.x;
    const int n0 = mb * 64;

    const int swz = swz_slot(lr, hg) << 4;        // (r&3),(r>>2)&3 dep only on lr
    const int aoff0 = (wr + lr) * 64 + swz;
    const int aoff1 = (wr + 16 + lr) * 64 + swz;
    int boff[4];
    #pragma unroll
    for (int n = 0; n < 4; ++n) boff[n] = (wc + n * 16 + lr) * 64 + swz;

    float b1[8], b2[8]; int i1[8];
    #pragma unroll
    for (int s = 0; s < 8; ++s) { b1[s] = FLT_MAX; b2[s] = FLT_MAX; i1[s] = 0; }

    const char* ztile_h = zt_hi + (size_t)mb * 16 * 4096;
    const char* ztile_l = zt_lo + (size_t)mb * 16 * 4096;
    const int toff = t * 16;

    f32x4 acc[2][4];
    #pragma unroll
    for (int m = 0; m < 2; ++m)
        #pragma unroll
        for (int n = 0; n < 4; ++n) acc[m][n] = (f32x4)(0.f);

    // prologue: stage s=0 (nc=0,kc=0) into buf 0
    {
        gld16(ztile_h + toff, sA[0] + toff);
        gld16(ztile_l + toff, sA[0] + 4096 + toff);
        gld16(et_hi + toff,        sB[0] + toff);
        gld16(et_hi + 4096 + toff, sB[0] + 4096 + toff);
        gld16(et_lo + toff,        sB[0] + 8192 + toff);
        gld16(et_lo + 4096 + toff, sB[0] + 12288 + toff);
    }
    __syncthreads();

    int buf = 0;
    for (int s = 0; s < 128; ++s) {
        // ---- issue next stage's loads into buf^1 (depth-1 prefetch)
        if (s + 1 < 128) {
            const int nn = (s + 1) >> 4, nk = (s + 1) & 15;
            const char* srcAh = ztile_h + (size_t)nk * 4096;
            const char* srcAl = ztile_l + (size_t)nk * 4096;
            const size_t tB = ((size_t)(nn * 16 + nk)) * 8192;
            char* dA = sA[buf ^ 1];
            char* dB = sB[buf ^ 1];
            gld16(srcAh + toff, dA + toff);
            gld16(srcAl + toff, dA + 4096 + toff);
            gld16(et_hi + tB + toff,        dB + toff);
            gld16(et_hi + tB + 4096 + toff, dB + 4096 + toff);
            gld16(et_lo + tB + toff,        dB + 8192 + toff);
            gld16(et_lo + tB + 4096 + toff, dB + 12288 + toff);
        }
        // ---- compute current stage from buf
        const char* A = sA[buf];
        const char* B = sB[buf];
        bf16x8 ah[2], al[2], bh[4], bl[4];
        ah[0] = *reinterpret_cast<const bf16x8*>(A + aoff0);
        ah[1] = *reinterpret_cast<const bf16x8*>(A + aoff1);
        al[0] = *reinterpret_cast<const bf16x8*>(A + 4096 + aoff0);
        al[1] = *reinterpret_cast<const bf16x8*>(A + 4096 + aoff1);
        #pragma unroll
        for (int n = 0; n < 4; ++n) {
            bh[n] = *reinterpret_cast<const bf16x8*>(B + boff[n]);
            bl[n] = *reinterpret_cast<const bf16x8*>(B + 8192 + boff[n]);
        }
        #pragma unroll
        for (int m = 0; m < 2; ++m)
            #pragma unroll
            for (int n = 0; n < 4; ++n)
                acc[m][n] = __builtin_amdgcn_mfma_f32_16x16x32_bf16(ah[m], bh[n], acc[m][n], 0, 0, 0);
        #pragma unroll
        for (int m = 0; m < 2; ++m)
            #pragma unroll
            for (int n = 0; n < 4; ++n)
                acc[m][n] = __builtin_amdgcn_mfma_f32_16x16x32_bf16(ah[m], bl[n], acc[m][n], 0, 0, 0);
        #pragma unroll
        for (int m = 0; m < 2; ++m)
            #pragma unroll
            for (int n = 0; n < 4; ++n)
                acc[m][n] = __builtin_amdgcn_mfma_f32_16x16x32_bf16(al[m], bh[n], acc[m][n], 0, 0, 0);

        // ---- end of an nc chunk: distances + running best-2 argmin
        if ((s & 15) == 15) {
            const int nc = s >> 4;
            #pragma unroll
            for (int n = 0; n < 4; ++n) {
                int col = nc * 128 + wc + n * 16 + lr;
                float en = enorm[col];
                #pragma unroll
                for (int m = 0; m < 2; ++m) {
                    #pragma unroll
                    for (int q = 0; q < 4; ++q) {
                        float dv = en - 2.0f * acc[m][n][q];
                        int sidx = m * 4 + q;
                        if (dv < b1[sidx]) { b2[sidx] = b1[sidx]; b1[sidx] = dv; i1[sidx] = col; }
                        else if (dv < b2[sidx]) b2[sidx] = dv;
                    }
                }
            }
            #pragma unroll
            for (int m = 0; m < 2; ++m)
                #pragma unroll
                for (int n = 0; n < 4; ++n) acc[m][n] = (f32x4)(0.f);
        }
        __syncthreads();   // drains prefetch vmcnt + guards buf^1 reuse
        buf ^= 1;
    }

    // cross-lane butterfly over the 16 column-lanes that share each row
    #pragma unroll
    for (int s = 0; s < 8; ++s) {
        #pragma unroll
        for (int off = 1; off <= 8; off <<= 1) {
            float ob1 = __shfl_xor(b1[s], off, 64);
            int   oi1 = __shfl_xor(i1[s], off, 64);
            float ob2 = __shfl_xor(b2[s], off, 64);
            if (ob1 < b1[s] || (ob1 == b1[s] && oi1 < i1[s])) {
                b2[s] = fminf(b1[s], ob2);
                b1[s] = ob1; i1[s] = oi1;
            } else {
                b2[s] = fminf(b2[s], ob1);
            }
        }
    }
    if (lr == 0) {
        #pragma unroll
        for (int s = 0; s < 8; ++s) {
            int row = wr + (s >> 2) * 16 + hg * 4 + (s & 3);
            red_b1[row][w & 1] = b1[s];
            red_b2[row][w & 1] = b2[s];
            red_i1[row][w & 1] = i1[s];
        }
    }
    __syncthreads();
    if (t < 64) {
        float a1 = red_b1[t][0], a2 = red_b2[t][0]; int ai = red_i1[t][0];
        float c1 = red_b1[t][1], c2 = red_b2[t][1]; int ci = red_i1[t][1];
        float B1, B2; int I1;
        if (c1 < a1 || (c1 == a1 && ci < ai)) { B1 = c1; I1 = ci; B2 = fminf(a1, c2); }
        else                                   { B1 = a1; I1 = ai; B2 = fminf(a2, c1); }
        idx_f[t] = I1;
        out[IOFF + n0 + t] = (float)I1;
        if (B2 - B1 < DELTA) {
            int pos = atomicAdd(cnt, 1);
            list[pos] = n0 + t;
        }
    }
    if (mb == 0 && t == 0) out[SOFF] = 0.0f;
    __syncthreads();

    // gather epilogue: out[b][c][hw0+row] = e[idx[row]][c]
    const int b   = n0 >> 10;
    const int hw0 = n0 & (HW - 1);
    const int row4 = (t & 15) * 4;
    const int i0 = idx_f[row4 + 0];
    const int i1g = idx_f[row4 + 1];
    const int i2 = idx_f[row4 + 2];
    const int i3 = idx_f[row4 + 3];
    #pragma unroll 4
    for (int p = 0; p < 32; ++p) {
        int c = (t >> 4) + (p << 4);
        float4 v;
        v.x = e[(size_t)i0  * DIM + c];
        v.y = e[(size_t)i1g * DIM + c];
        v.z = e[(size_t)i2  * DIM + c];
        v.w = e[(size_t)i3  * DIM + c];
        *reinterpret_cast<float4*>(&out[((size_t)(b * DIM + c)) * HW + hw0 + row4]) = v;
    }
}

// ---------------- Recheck: lane-parallel exact fp32 re-scan ----------------
__global__ __launch_bounds__(256) void recheck(const float* __restrict__ z,
                                               const float* __restrict__ e,
                                               const float* __restrict__ enorm,
                                               const int* __restrict__ cnt,
                                               const int* __restrict__ list,
                                               float* __restrict__ out) {
    __shared__ float zrow[512];
    __shared__ float rbest[256];
    __shared__ int   ribi[256];
    __shared__ int   s_fbi;
    const int t = threadIdx.x;
    const int count = *cnt;
    for (int i = blockIdx.x; i < count; i += gridDim.x) {
        const int row = list[i];
        const int b  = row >> 10;
        const int hw = row & (HW - 1);
        __syncthreads();   // guard zrow/rbest reuse across row iterations
        zrow[t]       = z[((size_t)(b * DIM + t))       * HW + hw];
        zrow[t + 256] = z[((size_t)(b * DIM + t + 256)) * HW + hw];
        __syncthreads();
        const float4* zr = reinterpret_cast<const float4*>(zrow);
        float best = FLT_MAX; int bi = 0;
        #pragma unroll
        for (int p = 0; p < 4; ++p) {     // ascending ke => strict < keeps lowest index
            const int ke = t + p * 256;
            const float4* ep = reinterpret_cast<const float4*>(e + (size_t)ke * DIM);
            float s0 = 0.f, s1 = 0.f, s2 = 0.f, s3 = 0.f;
            for (int c = 0; c < 128; c += 4) {
                float4 e0 = ep[c],     z0 = zr[c];
                float4 e1 = ep[c + 1], z1 = zr[c + 1];
                float4 e2 = ep[c + 2], z2 = zr[c + 2];
                float4 e3 = ep[c + 3], z3 = zr[c + 3];
                s0 += e0.x*z0.x + e0.y*z0.y + e0.z*z0.z + e0.w*z0.w;
                s1 += e1.x*z1.x + e1.y*z1.y + e1.z*z1.z + e1.w*z1.w;
                s2 += e2.x*z2.x + e2.y*z2.y + e2.z*z2.z + e2.w*z2.w;
                s3 += e3.x*z3.x + e3.y*z3.y + e3.z*z3.z + e3.w*z3.w;
            }
            float dist = enorm[ke] - 2.0f * (((s0 + s1) + (s2 + s3)));
            if (dist < best) { best = dist; bi = ke; }
        }
        rbest[t] = best; ribi[t] = bi;
        __syncthreads();
        #pragma unroll
        for (int s = 128; s > 0; s >>= 1) {
            if (t < s) {
                float ov = rbest[t + s]; int oi = ribi[t + s];
                if (ov < rbest[t] || (ov == rbest[t] && oi < ribi[t])) {
                    rbest[t] = ov; ribi[t] = oi;
                }
            }
            __syncthreads();
        }
        if (t == 0) {
            s_fbi = ribi[0];
            out[IOFF + row] = (float)ribi[0];
        }
        __syncthreads();
        const int fbi = s_fbi;
        out[((size_t)(b * DIM + t))       * HW + hw] = e[(size_t)fbi * DIM + t];
        out[((size_t)(b * DIM + t + 256)) * HW + hw] = e[(size_t)fbi * DIM + t + 256];
    }
}

// ======================= fp32 fallback path (round-2, proven) ================
constexpr int TM = 64;
constexpr int TN = 256;
constexpr int KC = 32;
constexpr int ZST = 68;
constexpr int EST = 260;

union F4 { float4 v; float f[4]; };

__global__ __launch_bounds__(256) void enorm_kernel(const float* __restrict__ e,
                                                    float* __restrict__ enorm) {
    int gid  = blockIdx.x * 256 + threadIdx.x;
    int wave = gid >> 6;
    int lane = gid & 63;
    if (wave >= NEMB) return;
    const float* row = e + (size_t)wave * DIM;
    float4 a = *reinterpret_cast<const float4*>(row + lane * 8);
    float4 b = *reinterpret_cast<const float4*>(row + lane * 8 + 4);
    float s = a.x*a.x + a.y*a.y + a.z*a.z + a.w*a.w
            + b.x*b.x + b.y*b.y + b.z*b.z + b.w*b.w;
    #pragma unroll
    for (int off = 32; off > 0; off >>= 1) s += __shfl_down(s, off, 64);
    if (lane == 0) enorm[wave] = s;
}

__global__ __launch_bounds__(256) void vq_main_kernel(const float* __restrict__ z,
                                                      const float* __restrict__ e,
                                                      const float* __restrict__ enorm,
                                                      float* __restrict__ out) {
    __shared__ float zs[KC][ZST];
    __shared__ float es[KC][EST];
    __shared__ float enorm_l[NEMB];
    __shared__ int   idx_f[TM];

    const int t   = threadIdx.x;
    const int n0  = blockIdx.x * TM;
    const int b   = n0 >> 10;
    const int hw0 = n0 & (HW - 1);
    const float* zb = z + ((size_t)b * DIM) * HW + hw0;

    #pragma unroll
    for (int i = 0; i < 4; ++i) enorm_l[t + i * 256] = enorm[t + i * 256];

    const int rg = t >> 5;
    const int cg = t & 31;

    float best[8];
    int   bidx[8];
    #pragma unroll
    for (int i = 0; i < 8; ++i) { best[i] = FLT_MAX; bidx[i] = 0; }

    const int z_r4 = (t & 15) * 4;
    const int z_c  = t >> 4;
    const int e_ke = t >> 3;
    const int e_c4 = t & 7;

    for (int nc = 0; nc < NEMB / TN; ++nc) {
        const int k0 = nc * TN;
        float acc[8][8];
        #pragma unroll
        for (int mi = 0; mi < 8; ++mi)
            #pragma unroll
            for (int nj = 0; nj < 8; ++nj) acc[mi][nj] = 0.f;

        for (int kc = 0; kc < DIM / KC; ++kc) {
            const int c0 = kc * KC;
            __syncthreads();
            #pragma unroll
            for (int p = 0; p < 2; ++p) {
                int c = z_c + p * 16;
                float4 v = *reinterpret_cast<const float4*>(zb + (size_t)(c0 + c) * HW + z_r4);
                *reinterpret_cast<float4*>(&zs[c][z_r4]) = v;
            }
            #pragma unroll
            for (int p = 0; p < 8; ++p) {
                int ke = e_ke + p * 32;
                float4 v = *reinterpret_cast<const float4*>(e + (size_t)(k0 + ke) * DIM + c0 + e_c4 * 4);
                es[e_c4 * 4 + 0][ke] = v.x;
                es[e_c4 * 4 + 1][ke] = v.y;
                es[e_c4 * 4 + 2][ke] = v.z;
                es[e_c4 * 4 + 3][ke] = v.w;
            }
            __syncthreads();
            #pragma unroll
            for (int kk = 0; kk < KC; ++kk) {
                F4 zf0, zf1, ef0, ef1;
                zf0.v = *reinterpret_cast<const float4*>(&zs[kk][rg * 8]);
                zf1.v = *reinterpret_cast<const float4*>(&zs[kk][rg * 8 + 4]);
                ef0.v = *reinterpret_cast<const float4*>(&es[kk][cg * 4]);
                ef1.v = *reinterpret_cast<const float4*>(&es[kk][128 + cg * 4]);
                #pragma unroll
                for (int mi = 0; mi < 4; ++mi) {
                    #pragma unroll
                    for (int nj = 0; nj < 4; ++nj) {
                        acc[mi][nj]         += zf0.f[mi] * ef0.f[nj];
                        acc[mi][nj + 4]     += zf0.f[mi] * ef1.f[nj];
                        acc[mi + 4][nj]     += zf1.f[mi] * ef0.f[nj];
                        acc[mi + 4][nj + 4] += zf1.f[mi] * ef1.f[nj];
                    }
                }
            }
        }
        #pragma unroll
        for (int mi = 0; mi < 8; ++mi) {
            #pragma unroll
            for (int nj = 0; nj < 8; ++nj) {
                int col = k0 + (nj < 4 ? cg * 4 + nj : 128 + cg * 4 + (nj - 4));
                float dv = enorm_l[col] - 2.0f * acc[mi][nj];
                if (dv < best[mi]) { best[mi] = dv; bidx[mi] = col; }
            }
        }
    }

    __syncthreads();
    float* best_l = reinterpret_cast<float*>(es);
    int*   idx_l  = reinterpret_cast<int*>(reinterpret_cast<char*>(es) + (size_t)TM * 33 * 4);
    #pragma unroll
    for (int mi = 0; mi < 8; ++mi) {
        int row = rg * 8 + mi;
        best_l[row * 33 + cg] = best[mi];
        idx_l[row * 33 + cg]  = bidx[mi];
    }
    __syncthreads();
    if (t < TM) {
        float bv = best_l[t * 33];
        int   bi = idx_l[t * 33];
        #pragma unroll
        for (int c = 1; c < 32; ++c) {
            float v  = best_l[t * 33 + c];
            int   ix = idx_l[t * 33 + c];
            if (v < bv || (v == bv && ix < bi)) { bv = v; bi = ix; }
        }
        idx_f[t] = bi;
        out[IOFF + n0 + t] = (float)bi;
    }
    if (blockIdx.x == 0 && t == 0) out[SOFF] = 0.0f;
    __syncthreads();

    const int row4 = (t & 15) * 4;
    const int i0 = idx_f[row4 + 0];
    const int i1 = idx_f[row4 + 1];
    const int i2 = idx_f[row4 + 2];
    const int i3 = idx_f[row4 + 3];
    #pragma unroll 4
    for (int p = 0; p < 32; ++p) {
        int c = (t >> 4) + (p << 4);
        float4 v;
        v.x = e[(size_t)i0 * DIM + c];
        v.y = e[(size_t)i1 * DIM + c];
        v.z = e[(size_t)i2 * DIM + c];
        v.w = e[(size_t)i3 * DIM + c];
        *reinterpret_cast<float4*>(&out[((size_t)(b * DIM + c)) * HW + hw0 + row4]) = v;
    }
}

// ---------------- host launcher ----------------
extern "C" void kernel_launch(void* const* d_in, const int* in_sizes, int n_in,
                              void* d_out, int out_size, void* d_ws, size_t ws_size,
                              hipStream_t stream) {
    const float* z = (const float*)d_in[0];
    const float* e = (const float*)d_in[1];
    float* out = (float*)d_out;
    char*  ws  = (char*)d_ws;

    if (ws_size >= WS_NEED) {
        char*  zt_hi = ws + WS_ZHI;
        char*  zt_lo = ws + WS_ZLO;
        char*  et_hi = ws + WS_EHI;
        char*  et_lo = ws + WS_ELO;
        float* enorm = (float*)(ws + WS_ENORM);
        int*   cnt   = (int*)(ws + WS_CNT);
        int*   list  = (int*)(ws + WS_LIST);

        hipLaunchKernelGGL(enorm_prep, dim3(NEMB / 4), dim3(256), 0, stream, e, enorm, cnt);
        hipLaunchKernelGGL(eprep,      dim3(256),      dim3(256), 0, stream, e, et_hi, et_lo);
        hipLaunchKernelGGL(zprep,      dim3(4096),     dim3(256), 0, stream, z, zt_hi, zt_lo);
        hipLaunchKernelGGL(vq_mfma,    dim3(NROW / 64), dim3(256), 0, stream,
                           zt_hi, zt_lo, et_hi, et_lo, enorm, e, out, cnt, list);
        hipLaunchKernelGGL(recheck,    dim3(256),      dim3(256), 0, stream,
                           z, e, enorm, cnt, list, out);
    } else {
        float* enorm = (float*)ws;
        hipLaunchKernelGGL(enorm_kernel,   dim3(NEMB / 4), dim3(256), 0, stream, e, enorm);
        hipLaunchKernelGGL(vq_main_kernel, dim3(NROW / TM), dim3(256), 0, stream,
                           z, e, enorm, out);
    }
}

// Round 7
// 346.223 us; speedup vs baseline: 1.0146x; 1.0146x over previous
//
#include <hip/hip_runtime.h>
#include <cfloat>

typedef short  bf16x8 __attribute__((ext_vector_type(8)));
typedef float  f32x4  __attribute__((ext_vector_type(4)));
typedef unsigned int  uint;
typedef unsigned short ushort;

// Problem constants
constexpr int DIM  = 512;
constexpr int NEMB = 1024;
constexpr int HW   = 1024;
constexpr int NROW = 32 * HW;   // 32768

constexpr long long QCOUNT = (long long)32 * 512 * 32 * 32; // 16777216
constexpr long long SOFF   = QCOUNT;
constexpr long long IOFF   = SOFF + 1;

// ---------------- ws layout (bytes) ----------------
// zt: 256 mb x 16 kc tiles of (128r x 32k bf16, swizzled) = 8KB -> 32 MB each
// et: 4 nc x 16 kc tiles of (256r x 32k bf16, swizzled) = 16KB  -> 1 MB each
constexpr size_t WS_ZHI   = 0;
constexpr size_t WS_ZLO   = 33554432;
constexpr size_t WS_EHI   = 67108864;
constexpr size_t WS_ELO   = 68157440;
constexpr size_t WS_ENORM = 69206016;
constexpr size_t WS_CNT   = 69210112;
constexpr size_t WS_LIST  = 69210368;
constexpr size_t WS_NEED  = WS_LIST + (size_t)NROW * 4;

constexpr float DELTA = 0.125f;  // recheck margin (>>100x bf16-split error bound)

// ---------------- helpers ----------------
__device__ __forceinline__ ushort bf16_rne(float x) {
    union { float f; uint u; } a; a.f = x;
    uint t = a.u + 0x7FFFu + ((a.u >> 16) & 1u);
    return (ushort)(t >> 16);
}
__device__ __forceinline__ float bf16_to_f(ushort h) {
    union { float f; uint u; } a; a.u = ((uint)h) << 16;
    return a.f;
}
__device__ __forceinline__ void gld16(const void* g, void* l) {
    __builtin_amdgcn_global_load_lds(
        (const __attribute__((address_space(1))) void*)g,
        (__attribute__((address_space(3))) void*)l, 16, 0, 0);
}
union PK8 { bf16x8 v; ushort u[8]; };

// granule swizzle for 32k-wide tiles (row = 64B = 4 x 16B granules):
// bank(first dword) = (r&1)*16 + slot*4. slot = g ^ ((r>>1)&3) balances
// the 256 bank-touches of a wave64 ds_read_b128 to the 8/bank minimum.
__device__ __forceinline__ int swz_slot(int r, int g) {
    return g ^ ((r >> 1) & 3);
}

// ---------------- P1: embedding norms + counter zero ----------------
__global__ __launch_bounds__(256) void enorm_prep(const float* __restrict__ e,
                                                  float* __restrict__ enorm,
                                                  int* __restrict__ cnt) {
    if (blockIdx.x == 0 && threadIdx.x == 0) *cnt = 0;
    int gid  = blockIdx.x * 256 + threadIdx.x;
    int wave = gid >> 6;
    int lane = gid & 63;
    if (wave >= NEMB) return;
    const float* row = e + (size_t)wave * DIM;
    float4 a = *reinterpret_cast<const float4*>(row + lane * 8);
    float4 b = *reinterpret_cast<const float4*>(row + lane * 8 + 4);
    float s = a.x*a.x + a.y*a.y + a.z*a.z + a.w*a.w
            + b.x*b.x + b.y*b.y + b.z*b.z + b.w*b.w;
    #pragma unroll
    for (int off = 32; off > 0; off >>= 1) s += __shfl_down(s, off, 64);
    if (lane == 0) enorm[wave] = s;
}

// ---------------- P2: e -> et_hi / et_lo swizzled 256x32 tiles -------------
__global__ __launch_bounds__(256) void eprep(const float* __restrict__ e,
                                             char* __restrict__ et_hi,
                                             char* __restrict__ et_lo) {
    int gid = blockIdx.x * 256 + threadIdx.x;  // 0..65535
    int ke  = gid >> 6;
    int kbg = gid & 63;                        // 16B-granule 0..63
    const float* src = e + (size_t)ke * DIM + kbg * 8;
    PK8 h, lo;
    #pragma unroll
    for (int j = 0; j < 8; ++j) {
        float v = src[j];
        ushort hh = bf16_rne(v);
        h.u[j]  = hh;
        lo.u[j] = bf16_rne(v - bf16_to_f(hh));
    }
    int nc = ke >> 8, r = ke & 255, kc = kbg >> 2, g = kbg & 3;
    size_t byte = ((size_t)(nc * 16 + kc)) * 16384 + (size_t)r * 64
                + ((size_t)swz_slot(r, g) << 4);
    *reinterpret_cast<bf16x8*>(et_hi + byte) = h.v;
    *reinterpret_cast<bf16x8*>(et_lo + byte) = lo.v;
}

// ---------------- P3: z -> zt_hi / zt_lo swizzled 128x32 tiles (transpose) -
__global__ __launch_bounds__(256) void zprep(const float* __restrict__ z,
                                             char* __restrict__ zt_hi,
                                             char* __restrict__ zt_lo) {
    __shared__ float ls[64][129];
    const int bx  = blockIdx.x;
    const int mb  = bx >> 3, kcc = bx & 7;     // kcc: 64-channel group
    const int b   = mb >> 3;                   // rows mb*128 -> batch
    const int hw0 = (mb & 7) * 128;
    const int t = threadIdx.x;
    // load 64 channels x 128 hw (coalesced 128-float runs)
    for (int i = t; i < 64 * 128; i += 256) {
        int c = i >> 7, hw = i & 127;
        ls[c][hw] = z[((size_t)(b * DIM + kcc * 64 + c)) * HW + hw0 + hw];
    }
    __syncthreads();
    // write swizzled granules: 128 rows x 8 granules (of 8 channels)
    for (int j = t; j < 1024; j += 256) {
        int r = j >> 3, kbl = j & 7;
        PK8 h, lo;
        #pragma unroll
        for (int jj = 0; jj < 8; ++jj) {
            float v = ls[kbl * 8 + jj][r];
            ushort hh = bf16_rne(v);
            h.u[jj]  = hh;
            lo.u[jj] = bf16_rne(v - bf16_to_f(hh));
        }
        int kc = kcc * 2 + (kbl >> 2), g = kbl & 3;
        size_t byte = ((size_t)(mb * 16 + kc)) * 8192 + (size_t)r * 64
                    + ((size_t)swz_slot(r, g) << 4);
        *reinterpret_cast<bf16x8*>(zt_hi + byte) = h.v;
        *reinterpret_cast<bf16x8*>(zt_lo + byte) = lo.v;
    }
}

// ---------------- Main: 128x256 tile, 8-wave, dbuf bf16-split MFMA ---------
__global__ __launch_bounds__(512, 2) void vq_mfma(const char* __restrict__ zt_hi,
                                                  const char* __restrict__ zt_lo,
                                                  const char* __restrict__ et_hi,
                                                  const char* __restrict__ et_lo,
                                                  const float* __restrict__ enorm,
                                                  const float* __restrict__ e,
                                                  float* __restrict__ out,
                                                  int* __restrict__ cnt,
                                                  int* __restrict__ list) {
    // layout: A0 16K | A1 16K | B0 32K | B1 32K
    __shared__ __align__(16) char smem[98304];

    const int t = threadIdx.x;
    const int w = t >> 6, l = t & 63;
    const int lr = l & 15, hg = l >> 4;          // hg = k-granule 0..3
    const int wrow = w >> 2;                      // 0..1  -> rows wrow*64
    const int wcol = w & 3;                       // 0..3  -> cols wcol*64
    const int mb = blockIdx.x;
    const int n0 = mb * 128;

    const int swz = swz_slot(lr, hg) << 4;        // base rows are mult of 16
    int aoff[4], boff[4];
    #pragma unroll
    for (int m = 0; m < 4; ++m) aoff[m] = (wrow * 64 + m * 16 + lr) * 64 + swz;
    #pragma unroll
    for (int n = 0; n < 4; ++n) boff[n] = (wcol * 64 + n * 16 + lr) * 64 + swz;

    float b1[16], b2[16]; int i1[16];
    #pragma unroll
    for (int s = 0; s < 16; ++s) { b1[s] = FLT_MAX; b2[s] = FLT_MAX; i1[s] = 0; }

    const char* ztile_h = zt_hi + (size_t)mb * 16 * 8192;
    const char* ztile_l = zt_lo + (size_t)mb * 16 * 8192;
    const int toff = t * 16;

    f32x4 acc[4][4];
    #pragma unroll
    for (int m = 0; m < 4; ++m)
        #pragma unroll
        for (int n = 0; n < 4; ++n) acc[m][n] = (f32x4)(0.f);

    // prologue: stage step 0 (nc=0,kc=0) into buf 0
    {
        char* dA = smem;            // A0
        char* dB = smem + 32768;    // B0
        gld16(ztile_h + toff, dA + toff);           // A hi (8KB)
        gld16(ztile_l + toff, dA + 8192 + toff);    // A lo
        gld16(et_hi + toff,         dB + toff);     // B hi (16KB)
        gld16(et_hi + 8192 + toff,  dB + 8192 + toff);
        gld16(et_lo + toff,         dB + 16384 + toff);
        gld16(et_lo + 8192 + toff,  dB + 24576 + toff);
    }
    __syncthreads();

    int buf = 0;
    for (int s = 0; s < 64; ++s) {
        // ---- prefetch next step into buf^1
        if (s + 1 < 64) {
            const int nn = (s + 1) >> 4, nk = (s + 1) & 15;
            char* dA = smem + (buf ? 0 : 16384);
            char* dB = smem + 32768 + (buf ? 0 : 32768);
            const size_t tB = ((size_t)(nn * 16 + nk)) * 16384;
            gld16(ztile_h + (size_t)nk * 8192 + toff, dA + toff);
            gld16(ztile_l + (size_t)nk * 8192 + toff, dA + 8192 + toff);
            gld16(et_hi + tB + toff,        dB + toff);
            gld16(et_hi + tB + 8192 + toff, dB + 8192 + toff);
            gld16(et_lo + tB + toff,        dB + 16384 + toff);
            gld16(et_lo + tB + 8192 + toff, dB + 24576 + toff);
        }
        // ---- compute current step from buf
        const char* A = smem + (buf ? 16384 : 0);
        const char* B = smem + 32768 + (buf ? 32768 : 0);
        bf16x8 ah[4], al[4], bh[4], bl[4];
        #pragma unroll
        for (int m = 0; m < 4; ++m) {
            ah[m] = *reinterpret_cast<const bf16x8*>(A + aoff[m]);
            al[m] = *reinterpret_cast<const bf16x8*>(A + 8192 + aoff[m]);
        }
        #pragma unroll
        for (int n = 0; n < 4; ++n) {
            bh[n] = *reinterpret_cast<const bf16x8*>(B + boff[n]);
            bl[n] = *reinterpret_cast<const bf16x8*>(B + 16384 + boff[n]);
        }
        #pragma unroll
        for (int m = 0; m < 4; ++m)
            #pragma unroll
            for (int n = 0; n < 4; ++n)
                acc[m][n] = __builtin_amdgcn_mfma_f32_16x16x32_bf16(ah[m], bh[n], acc[m][n], 0, 0, 0);
        #pragma unroll
        for (int m = 0; m < 4; ++m)
            #pragma unroll
            for (int n = 0; n < 4; ++n)
                acc[m][n] = __builtin_amdgcn_mfma_f32_16x16x32_bf16(ah[m], bl[n], acc[m][n], 0, 0, 0);
        #pragma unroll
        for (int m = 0; m < 4; ++m)
            #pragma unroll
            for (int n = 0; n < 4; ++n)
                acc[m][n] = __builtin_amdgcn_mfma_f32_16x16x32_bf16(al[m], bh[n], acc[m][n], 0, 0, 0);

        // ---- end of an nc chunk: distances + running best-2 argmin
        if ((s & 15) == 15) {
            const int nc = s >> 4;
            #pragma unroll
            for (int n = 0; n < 4; ++n) {
                int col = nc * 256 + wcol * 64 + n * 16 + lr;
                float en = enorm[col];
                #pragma unroll
                for (int m = 0; m < 4; ++m) {
                    #pragma unroll
                    for (int q = 0; q < 4; ++q) {
                        float dv = en - 2.0f * acc[m][n][q];
                        int sl = m * 4 + q;
                        if (dv < b1[sl]) { b2[sl] = b1[sl]; b1[sl] = dv; i1[sl] = col; }
                        else if (dv < b2[sl]) b2[sl] = dv;
                    }
                }
            }
            #pragma unroll
            for (int m = 0; m < 4; ++m)
                #pragma unroll
                for (int n = 0; n < 4; ++n) acc[m][n] = (f32x4)(0.f);
        }
        __syncthreads();   // drains prefetch vmcnt + guards buf reuse
        buf ^= 1;
    }

    // ---- cross-lane butterfly over the 16 col-lanes sharing each row
    #pragma unroll
    for (int s = 0; s < 16; ++s) {
        #pragma unroll
        for (int off = 1; off <= 8; off <<= 1) {
            float ob1 = __shfl_xor(b1[s], off, 64);
            int   oi1 = __shfl_xor(i1[s], off, 64);
            float ob2 = __shfl_xor(b2[s], off, 64);
            if (ob1 < b1[s] || (ob1 == b1[s] && oi1 < i1[s])) {
                b2[s] = fminf(b1[s], ob2);
                b1[s] = ob1; i1[s] = oi1;
            } else {
                b2[s] = fminf(b2[s], ob1);
            }
        }
    }
    // ---- block reduction across the 4 col-waves (overlay on B0 region)
    float* red_b1 = reinterpret_cast<float*>(smem + 32768);         // [128][4]
    float* red_b2 = reinterpret_cast<float*>(smem + 32768 + 2048);  // [128][4]
    int*   red_i1 = reinterpret_cast<int*>  (smem + 32768 + 4096);  // [128][4]
    int*   idx_f  = reinterpret_cast<int*>  (smem + 32768 + 6144);  // [128]
    if (lr == 0) {
        #pragma unroll
        for (int s = 0; s < 16; ++s) {
            int row = wrow * 64 + (s >> 2) * 16 + hg * 4 + (s & 3);
            red_b1[row * 4 + wcol] = b1[s];
            red_b2[row * 4 + wcol] = b2[s];
            red_i1[row * 4 + wcol] = i1[s];
        }
    }
    __syncthreads();
    if (t < 128) {
        float B1 = red_b1[t * 4], B2 = red_b2[t * 4];
        int   I1 = red_i1[t * 4];
        #pragma unroll
        for (int c = 1; c < 4; ++c) {
            float c1 = red_b1[t * 4 + c], c2 = red_b2[t * 4 + c];
            int   ci = red_i1[t * 4 + c];
            if (c1 < B1 || (c1 == B1 && ci < I1)) { B2 = fminf(B1, c2); B1 = c1; I1 = ci; }
            else                                   { B2 = fminf(B2, c1); }
        }
        idx_f[t] = I1;
        out[IOFF + n0 + t] = (float)I1;
        if (B2 - B1 < DELTA) {
            int pos = atomicAdd(cnt, 1);
            list[pos] = n0 + t;
        }
    }
    if (mb == 0 && t == 0) out[SOFF] = 0.0f;
    __syncthreads();

    // ---- gather epilogue: out[b][c][hw0+row] = e[idx[row]][c]
    const int b   = mb >> 3;
    const int hw0 = (mb & 7) * 128;
    const int row4 = (t & 31) * 4;
    const int i0 = idx_f[row4 + 0];
    const int i1g = idx_f[row4 + 1];
    const int i2 = idx_f[row4 + 2];
    const int i3 = idx_f[row4 + 3];
    const int cbase = t >> 5;   // 0..15
    #pragma unroll 4
    for (int p = 0; p < 32; ++p) {
        int c = cbase + (p << 4);
        float4 v;
        v.x = e[(size_t)i0  * DIM + c];
        v.y = e[(size_t)i1g * DIM + c];
        v.z = e[(size_t)i2  * DIM + c];
        v.w = e[(size_t)i3  * DIM + c];
        *reinterpret_cast<float4*>(&out[((size_t)(b * DIM + c)) * HW + hw0 + row4]) = v;
    }
}

// ---------------- Recheck: lane-parallel exact fp32 re-scan ----------------
__global__ __launch_bounds__(256) void recheck(const float* __restrict__ z,
                                               const float* __restrict__ e,
                                               const float* __restrict__ enorm,
                                               const int* __restrict__ cnt,
                                               const int* __restrict__ list,
                                               float* __restrict__ out) {
    __shared__ float zrow[512];
    __shared__ float rbest[256];
    __shared__ int   ribi[256];
    __shared__ int   s_fbi;
    const int t = threadIdx.x;
    const int count = *cnt;
    for (int i = blockIdx.x; i < count; i += gridDim.x) {
        const int row = list[i];
        const int b  = row >> 10;
        const int hw = row & (HW - 1);
        __syncthreads();
        zrow[t]       = z[((size_t)(b * DIM + t))       * HW + hw];
        zrow[t + 256] = z[((size_t)(b * DIM + t + 256)) * HW + hw];
        __syncthreads();
        const float4* zr = reinterpret_cast<const float4*>(zrow);
        float best = FLT_MAX; int bi = 0;
        #pragma unroll
        for (int p = 0; p < 4; ++p) {     // ascending ke => strict < keeps lowest index
            const int ke = t + p * 256;
            const float4* ep = reinterpret_cast<const float4*>(e + (size_t)ke * DIM);
            float s0 = 0.f, s1 = 0.f, s2 = 0.f, s3 = 0.f;
            for (int c = 0; c < 128; c += 4) {
                float4 e0 = ep[c],     z0 = zr[c];
                float4 e1 = ep[c + 1], z1 = zr[c + 1];
                float4 e2 = ep[c + 2], z2 = zr[c + 2];
                float4 e3 = ep[c + 3], z3 = zr[c + 3];
                s0 += e0.x*z0.x + e0.y*z0.y + e0.z*z0.z + e0.w*z0.w;
                s1 += e1.x*z1.x + e1.y*z1.y + e1.z*z1.z + e1.w*z1.w;
                s2 += e2.x*z2.x + e2.y*z2.y + e2.z*z2.z + e2.w*z2.w;
                s3 += e3.x*z3.x + e3.y*z3.y + e3.z*z3.z + e3.w*z3.w;
            }
            float dist = enorm[ke] - 2.0f * (((s0 + s1) + (s2 + s3)));
            if (dist < best) { best = dist; bi = ke; }
        }
        rbest[t] = best; ribi[t] = bi;
        __syncthreads();
        #pragma unroll
        for (int s = 128; s > 0; s >>= 1) {
            if (t < s) {
                float ov = rbest[t + s]; int oi = ribi[t + s];
                if (ov < rbest[t] || (ov == rbest[t] && oi < ribi[t])) {
                    rbest[t] = ov; ribi[t] = oi;
                }
            }
            __syncthreads();
        }
        if (t == 0) {
            s_fbi = ribi[0];
            out[IOFF + row] = (float)ribi[0];
        }
        __syncthreads();
        const int fbi = s_fbi;
        out[((size_t)(b * DIM + t))       * HW + hw] = e[(size_t)fbi * DIM + t];
        out[((size_t)(b * DIM + t + 256)) * HW + hw] = e[(size_t)fbi * DIM + t + 256];
    }
}

// ======================= fp32 fallback path (round-2, proven) ================
constexpr int TM = 64;
constexpr int TN = 256;
constexpr int KC = 32;
constexpr int ZST = 68;
constexpr int EST = 260;

union F4 { float4 v; float f[4]; };

__global__ __launch_bounds__(256) void enorm_kernel(const float* __restrict__ e,
                                                    float* __restrict__ enorm) {
    int gid  = blockIdx.x * 256 + threadIdx.x;
    int wave = gid >> 6;
    int lane = gid & 63;
    if (wave >= NEMB) return;
    const float* row = e + (size_t)wave * DIM;
    float4 a = *reinterpret_cast<const float4*>(row + lane * 8);
    float4 b = *reinterpret_cast<const float4*>(row + lane * 8 + 4);
    float s = a.x*a.x + a.y*a.y + a.z*a.z + a.w*a.w
            + b.x*b.x + b.y*b.y + b.z*b.z + b.w*b.w;
    #pragma unroll
    for (int off = 32; off > 0; off >>= 1) s += __shfl_down(s, off, 64);
    if (lane == 0) enorm[wave] = s;
}

__global__ __launch_bounds__(256) void vq_main_kernel(const float* __restrict__ z,
                                                      const float* __restrict__ e,
                                                      const float* __restrict__ enorm,
                                                      float* __restrict__ out) {
    __shared__ float zs[KC][ZST];
    __shared__ float es[KC][EST];
    __shared__ float enorm_l[NEMB];
    __shared__ int   idx_f[TM];

    const int t   = threadIdx.x;
    const int n0  = blockIdx.x * TM;
    const int b   = n0 >> 10;
    const int hw0 = n0 & (HW - 1);
    const float* zb = z + ((size_t)b * DIM) * HW + hw0;

    #pragma unroll
    for (int i = 0; i < 4; ++i) enorm_l[t + i * 256] = enorm[t + i * 256];

    const int rg = t >> 5;
    const int cg = t & 31;

    float best[8];
    int   bidx[8];
    #pragma unroll
    for (int i = 0; i < 8; ++i) { best[i] = FLT_MAX; bidx[i] = 0; }

    const int z_r4 = (t & 15) * 4;
    const int z_c  = t >> 4;
    const int e_ke = t >> 3;
    const int e_c4 = t & 7;

    for (int nc = 0; nc < NEMB / TN; ++nc) {
        const int k0 = nc * TN;
        float acc[8][8];
        #pragma unroll
        for (int mi = 0; mi < 8; ++mi)
            #pragma unroll
            for (int nj = 0; nj < 8; ++nj) acc[mi][nj] = 0.f;

        for (int kc = 0; kc < DIM / KC; ++kc) {
            const int c0 = kc * KC;
            __syncthreads();
            #pragma unroll
            for (int p = 0; p < 2; ++p) {
                int c = z_c + p * 16;
                float4 v = *reinterpret_cast<const float4*>(zb + (size_t)(c0 + c) * HW + z_r4);
                *reinterpret_cast<float4*>(&zs[c][z_r4]) = v;
            }
            #pragma unroll
            for (int p = 0; p < 8; ++p) {
                int ke = e_ke + p * 32;
                float4 v = *reinterpret_cast<const float4*>(e + (size_t)(k0 + ke) * DIM + c0 + e_c4 * 4);
                es[e_c4 * 4 + 0][ke] = v.x;
                es[e_c4 * 4 + 1][ke] = v.y;
                es[e_c4 * 4 + 2][ke] = v.z;
                es[e_c4 * 4 + 3][ke] = v.w;
            }
            __syncthreads();
            #pragma unroll
            for (int kk = 0; kk < KC; ++kk) {
                F4 zf0, zf1, ef0, ef1;
                zf0.v = *reinterpret_cast<const float4*>(&zs[kk][rg * 8]);
                zf1.v = *reinterpret_cast<const float4*>(&zs[kk][rg * 8 + 4]);
                ef0.v = *reinterpret_cast<const float4*>(&es[kk][cg * 4]);
                ef1.v = *reinterpret_cast<const float4*>(&es[kk][128 + cg * 4]);
                #pragma unroll
                for (int mi = 0; mi < 4; ++mi) {
                    #pragma unroll
                    for (int nj = 0; nj < 4; ++nj) {
                        acc[mi][nj]         += zf0.f[mi] * ef0.f[nj];
                        acc[mi][nj + 4]     += zf0.f[mi] * ef1.f[nj];
                        acc[mi + 4][nj]     += zf1.f[mi] * ef0.f[nj];
                        acc[mi + 4][nj + 4] += zf1.f[mi] * ef1.f[nj];
                    }
                }
            }
        }
        #pragma unroll
        for (int mi = 0; mi < 8; ++mi) {
            #pragma unroll
            for (int nj = 0; nj < 8; ++nj) {
                int col = k0 + (nj < 4 ? cg * 4 + nj : 128 + cg * 4 + (nj - 4));
                float dv = enorm_l[col] - 2.0f * acc[mi][nj];
                if (dv < best[mi]) { best[mi] = dv; bidx[mi] = col; }
            }
        }
    }

    __syncthreads();
    float* best_l = reinterpret_cast<float*>(es);
    int*   idx_l  = reinterpret_cast<int*>(reinterpret_cast<char*>(es) + (size_t)TM * 33 * 4);
    #pragma unroll
    for (int mi = 0; mi < 8; ++mi) {
        int row = rg * 8 + mi;
        best_l[row * 33 + cg] = best[mi];
        idx_l[row * 33 + cg]  = bidx[mi];
    }
    __syncthreads();
    if (t < TM) {
        float bv = best_l[t * 33];
        int   bi = idx_l[t * 33];
        #pragma unroll
        for (int c = 1; c < 32; ++c) {
            float v  = best_l[t * 33 + c];
            int   ix = idx_l[t * 33 + c];
            if (v < bv || (v == bv && ix < bi)) { bv = v; bi = ix; }
        }
        idx_f[t] = bi;
        out[IOFF + n0 + t] = (float)bi;
    }
    if (blockIdx.x == 0 && t == 0) out[SOFF] = 0.0f;
    __syncthreads();

    const int row4 = (t & 15) * 4;
    const int i0 = idx_f[row4 + 0];
    const int i1 = idx_f[row4 + 1];
    const int i2 = idx_f[row4 + 2];
    const int i3 = idx_f[row4 + 3];
    #pragma unroll 4
    for (int p = 0; p < 32; ++p) {
        int c = (t >> 4) + (p << 4);
        float4 v;
        v.x = e[(size_t)i0 * DIM + c];
        v.y = e[(size_t)i1 * DIM + c];
        v.z = e[(size_t)i2 * DIM + c];
        v.w = e[(size_t)i3 * DIM + c];
        *reinterpret_cast<float4*>(&out[((size_t)(b * DIM + c)) * HW + hw0 + row4]) = v;
    }
}

// ---------------- host launcher ----------------
extern "C" void kernel_launch(void* const* d_in, const int* in_sizes, int n_in,
                              void* d_out, int out_size, void* d_ws, size_t ws_size,
                              hipStream_t stream) {
    const float* z = (const float*)d_in[0];
    const float* e = (const float*)d_in[1];
    float* out = (float*)d_out;
    char*  ws  = (char*)d_ws;

    if (ws_size >= WS_NEED) {
        char*  zt_hi = ws + WS_ZHI;
        char*  zt_lo = ws + WS_ZLO;
        char*  et_hi = ws + WS_EHI;
        char*  et_lo = ws + WS_ELO;
        float* enorm = (float*)(ws + WS_ENORM);
        int*   cnt   = (int*)(ws + WS_CNT);
        int*   list  = (int*)(ws + WS_LIST);

        hipLaunchKernelGGL(enorm_prep, dim3(NEMB / 4), dim3(256), 0, stream, e, enorm, cnt);
        hipLaunchKernelGGL(eprep,      dim3(256),      dim3(256), 0, stream, e, et_hi, et_lo);
        hipLaunchKernelGGL(zprep,      dim3(2048),     dim3(256), 0, stream, z, zt_hi, zt_lo);
        hipLaunchKernelGGL(vq_mfma,    dim3(NROW / 128), dim3(512), 0, stream,
                           zt_hi, zt_lo, et_hi, et_lo, enorm, e, out, cnt, list);
        hipLaunchKernelGGL(recheck,    dim3(256),      dim3(256), 0, stream,
                           z, e, enorm, cnt, list, out);
    } else {
        float* enorm = (float*)ws;
        hipLaunchKernelGGL(enorm_kernel,   dim3(NEMB / 4), dim3(256), 0, stream, e, enorm);
        hipLaunchKernelGGL(vq_main_kernel, dim3(NROW / TM), dim3(256), 0, stream,
                           z, e, enorm, out);
    }
}